// Round 8
// baseline (173.256 us; speedup 1.0000x reference)
//
#include <hip/hip_runtime.h>
#include <hip/hip_bf16.h>

#define B_     4
#define V_IN   12500
#define V_OUT  50000
#define C_IN   64
#define C_OUT  32
#define SPIRAL 9
#define K_NNZ  3
#define ROWS   (B_ * V_OUT)       // 200000
#define KDIM   (SPIRAL * C_IN)    // 576
#define KSTEPS (KDIM / 32)        // 18 (16x16x32 MFMA)
#define WFRAG_ELEMS (KSTEPS * 2 * 64 * 8)  // 18432 bf16 = 36864 B

#define GROUPS_PER_B (V_OUT / 16) // 3125 16-row groups per batch (k1)
#define G1           2048         // k1 blocks (+1 W-prep); 256 per XCD
#define TILES_PER_B  782          // 781 full 64-row tiles + one 16-row tail (k2)
#define G2           512          // k2 blocks; 64 per XCD; 2 blocks/CU

typedef __attribute__((ext_vector_type(8))) short short8_t;   // 8 bf16 (4 VGPRs)
typedef __attribute__((ext_vector_type(4))) float floatx4;    // 4 fp32 acc

__device__ __forceinline__ unsigned short f32_to_bf16(float f) {
    unsigned int u = __float_as_uint(f);
    unsigned int r = u + 0x7fffu + ((u >> 16) & 1u);   // round-to-nearest-even
    return (unsigned short)(r >> 16);
}

// ---------------- Kernel 1: upsample (idx-prefetch pipelined) ----------------
// up[b,v,c] = sum_k x[b,up_idx[v,k],c]*up_val[v,k] -> bf16 in ws.
// XCD-swizzled: block i serves batch b=(i&7)>>1 (x[b]=3.2MB stays in XCD L2).
// Block G1: rearrange weight (576x32 fp32) into MFMA fragment order (bf16):
//   w_frag[((kstep*2+ntile)*64+lane)*8+j] = W[kstep*32+(lane>>4)*8+j][ntile*16+(lane&15)]
__global__ __launch_bounds__(256) void upsample_kernel(
    const float* __restrict__ x,
    const int* __restrict__ up_idx,
    const float* __restrict__ up_val,
    const float* __restrict__ weight,
    unsigned short* __restrict__ up_bf16,
    unsigned short* __restrict__ w_frag)
{
    int tid = threadIdx.x;
    if (blockIdx.x == G1) {
        for (int idx = tid; idx < WFRAG_ELEMS; idx += 256) {
            int j     = idx & 7;
            int lane  = (idx >> 3) & 63;
            int ntile = (idx >> 9) & 1;
            int kstep = idx >> 10;
            int k = kstep * 32 + (lane >> 4) * 8 + j;
            int n = ntile * 16 + (lane & 15);
            w_frag[idx] = f32_to_bf16(weight[k * C_OUT + n]);
        }
        return;
    }
    int xcd = blockIdx.x & 7;
    int b   = xcd >> 1;                     // batch owned by this XCD pair
    int h   = xcd & 1;
    int j   = blockIdx.x >> 3;              // [0, 256)
    int slot = h + 2 * j;                   // [0, 512)
    int lane16 = tid & 15;                  // 4 channels each
    int sub    = tid >> 4;                  // row within 16-row group

    const float* xb = x + (size_t)b * V_IN * C_IN;
    unsigned short* upb = up_bf16 + (size_t)b * V_OUT * C_IN;

    int gl = slot;
    if (gl >= GROUPS_PER_B) return;
    int v = gl * 16 + sub;
    int   u0 = up_idx[v * K_NNZ + 0], u1 = up_idx[v * K_NNZ + 1], u2 = up_idx[v * K_NNZ + 2];
    float c0 = up_val[v * K_NNZ + 0], c1 = up_val[v * K_NNZ + 1], c2 = up_val[v * K_NNZ + 2];

    while (true) {
        int gln = gl + 512;
        int un0 = 0, un1 = 0, un2 = 0; float cn0 = 0, cn1 = 0, cn2 = 0;
        if (gln < GROUPS_PER_B) {           // prefetch next group's indices
            int vn = gln * 16 + sub;
            un0 = up_idx[vn * K_NNZ + 0]; un1 = up_idx[vn * K_NNZ + 1]; un2 = up_idx[vn * K_NNZ + 2];
            cn0 = up_val[vn * K_NNZ + 0]; cn1 = up_val[vn * K_NNZ + 1]; cn2 = up_val[vn * K_NNZ + 2];
        }
        float4 x0 = *((const float4*)(xb + (size_t)u0 * C_IN) + lane16);
        float4 x1 = *((const float4*)(xb + (size_t)u1 * C_IN) + lane16);
        float4 x2 = *((const float4*)(xb + (size_t)u2 * C_IN) + lane16);
        float a0 = c0 * x0.x + c1 * x1.x + c2 * x2.x;
        float a1 = c0 * x0.y + c1 * x1.y + c2 * x2.y;
        float a2 = c0 * x0.z + c1 * x1.z + c2 * x2.z;
        float a3 = c0 * x0.w + c1 * x1.w + c2 * x2.w;
        ushort4 o;
        o.x = f32_to_bf16(a0); o.y = f32_to_bf16(a1);
        o.z = f32_to_bf16(a2); o.w = f32_to_bf16(a3);
        *((ushort4*)(upb + (size_t)(gl * 16 + sub) * C_IN) + lane16) = o;
        if (gln >= GROUPS_PER_B) break;
        gl = gln;
        u0 = un0; u1 = un1; u2 = un2; c0 = cn0; c1 = cn1; c2 = cn2;
    }
}

// ---------------- Kernel 2: gather + MFMA gemm (2-stage pipelined) ----------
__device__ __forceinline__ void load_sp(int* dst, const int* __restrict__ spiral,
                                        int t, int wave, int m) {
    int vr = t * 64 + wave * 16 + m;
    int v = vr < V_OUT ? vr : 0;
    const int* sp = spiral + v * SPIRAL;
#pragma unroll
    for (int s = 0; s < SPIRAL; s++) dst[s] = sp[s];
}

__device__ __forceinline__ void load_g(short8_t (*g)[2], const int* sp,
                                       const unsigned short* __restrict__ upb, int quad) {
#pragma unroll
    for (int s = 0; s < SPIRAL; s++) {
        const unsigned short* rowp = upb + (size_t)sp[s] * C_IN;
        g[s][0] = *(const short8_t*)(rowp + quad * 8);
        g[s][1] = *(const short8_t*)(rowp + 32 + quad * 8);
    }
}

__device__ __forceinline__ void compute_store(const short8_t (*g)[2],
    const unsigned short* w_lds, int t, int wave, int lane, int m, int quad,
    float4 bias0, float4 bias1, float* __restrict__ outb)
{
    floatx4 acc0 = {0.f, 0.f, 0.f, 0.f};
    floatx4 acc1 = {0.f, 0.f, 0.f, 0.f};
#pragma unroll
    for (int kstep = 0; kstep < KSTEPS; kstep++) {
        short8_t gf = g[kstep >> 1][kstep & 1];
        const short8_t* wp0 = (const short8_t*)(w_lds + ((kstep * 2 + 0) * 64 + lane) * 8);
        const short8_t* wp1 = (const short8_t*)(w_lds + ((kstep * 2 + 1) * 64 + lane) * 8);
        acc0 = __builtin_amdgcn_mfma_f32_16x16x32_bf16(*wp0, gf, acc0, 0, 0, 0);
        acc1 = __builtin_amdgcn_mfma_f32_16x16x32_bf16(*wp1, gf, acc1, 0, 0, 0);
    }
    int vr = t * 64 + wave * 16 + m;
    if (vr < V_OUT) {
        float4 o0, o1;
        o0.x = acc0[0] + bias0.x; o0.y = acc0[1] + bias0.y;
        o0.z = acc0[2] + bias0.z; o0.w = acc0[3] + bias0.w;
        o1.x = acc1[0] + bias1.x; o1.y = acc1[1] + bias1.y;
        o1.z = acc1[2] + bias1.z; o1.w = acc1[3] + bias1.w;
        o0.x = o0.x > 0.f ? o0.x : 0.f;  o0.y = o0.y > 0.f ? o0.y : 0.f;
        o0.z = o0.z > 0.f ? o0.z : 0.f;  o0.w = o0.w > 0.f ? o0.w : 0.f;
        o1.x = o1.x > 0.f ? o1.x : 0.f;  o1.y = o1.y > 0.f ? o1.y : 0.f;
        o1.z = o1.z > 0.f ? o1.z : 0.f;  o1.w = o1.w > 0.f ? o1.w : 0.f;
        float* op = outb + (size_t)vr * C_OUT;
        *(float4*)(op + quad * 4)      = o0;
        *(float4*)(op + 16 + quad * 4) = o1;
    }
}

// Pipeline: sp-indices 2 tiles ahead, g-gathers 1 tile ahead; the gather of
// tile t+1 overlaps the 36-MFMA chain of tile t (compiler emits vmcnt(N>0)
// since no barrier/LDS-DMA sits between issue and use).
__global__ __launch_bounds__(256, 2) void gemm_kernel(
    const unsigned short* __restrict__ up_bf16,
    const int* __restrict__ spiral,
    const unsigned short* __restrict__ w_frag,
    const float* __restrict__ bias,
    float* __restrict__ out)
{
    __shared__ __align__(16) unsigned short w_lds[WFRAG_ELEMS];  // 36864 B
    int tid = threadIdx.x;
    {   // stage W fragments to LDS once per block
        const uint4* src = (const uint4*)w_frag;
        uint4* dst = (uint4*)w_lds;
#pragma unroll
        for (int i = 0; i < WFRAG_ELEMS / 8 / 256; i++)
            dst[tid + i * 256] = src[tid + i * 256];
    }
    __syncthreads();

    int wave = tid >> 6;
    int lane = tid & 63;
    int m    = lane & 15;
    int quad = lane >> 4;

    int xcd  = blockIdx.x & 7;
    int b    = xcd >> 1;
    int h    = xcd & 1;
    int j    = blockIdx.x >> 3;             // [0, 64)
    int slot = h + 2 * j;                   // [0, 128)

    const unsigned short* upb = up_bf16 + (size_t)b * V_OUT * C_IN;
    float* outb = out + (size_t)b * V_OUT * C_OUT;

    float4 bias0 = ((const float4*)bias)[quad];      // bias[quad*4 .. +3]
    float4 bias1 = ((const float4*)bias)[4 + quad];  // bias[16+quad*4 .. +3]

    int nt = (TILES_PER_B - 1 - slot) / 128 + 1;     // 6 or 7 tiles (uniform/block)

    int      spb[2][SPIRAL];
    short8_t gb[2][SPIRAL][2];
    load_sp(spb[0], spiral, slot, wave, m);
    load_sp(spb[1], spiral, slot + 128, wave, m);    // nt >= 6 always
    load_g(gb[0], spb[0], upb, quad);

    int i = 0;
    while (true) {
        // body(i), cur = 0
        if (i + 1 < nt) load_g(gb[1], spb[1], upb, quad);
        if (i + 2 < nt) load_sp(spb[0], spiral, slot + (i + 2) * 128, wave, m);
        compute_store(gb[0], w_lds, slot + i * 128, wave, lane, m, quad, bias0, bias1, outb);
        if (++i == nt) break;
        // body(i), cur = 1
        if (i + 1 < nt) load_g(gb[0], spb[0], upb, quad);
        if (i + 2 < nt) load_sp(spb[1], spiral, slot + (i + 2) * 128, wave, m);
        compute_store(gb[1], w_lds, slot + i * 128, wave, lane, m, quad, bias0, bias1, outb);
        if (++i == nt) break;
    }
}

extern "C" void kernel_launch(void* const* d_in, const int* in_sizes, int n_in,
                              void* d_out, int out_size, void* d_ws, size_t ws_size,
                              hipStream_t stream) {
    const float* x      = (const float*)d_in[0];
    const int*   spiral = (const int*)d_in[1];
    const int*   up_idx = (const int*)d_in[2];
    const float* up_val = (const float*)d_in[3];
    const float* weight = (const float*)d_in[4];
    const float* bias   = (const float*)d_in[5];
    float* out = (float*)d_out;

    unsigned short* up_ws  = (unsigned short*)d_ws;          // 200000*64 bf16 = 25.6 MB
    unsigned short* w_frag = up_ws + (size_t)ROWS * C_IN;    // + 36864 B

    upsample_kernel<<<G1 + 1, 256, 0, stream>>>(x, up_idx, up_val, weight, up_ws, w_frag);
    gemm_kernel<<<G2, 256, 0, stream>>>(up_ws, spiral, w_frag, bias, out);
}